// Round 7
// baseline (955.837 us; speedup 1.0000x reference)
//
#include <hip/hip_runtime.h>
#include <cstdio>

// Qwen2 MoE sparse block, MI355X gfx950.
// Round 7: register-staged GEMM (global_load -> VGPR -> ds_write), NO
// global_load_lds (R1-R6 all latency-serialized at ~1 block/CU with it).
// 128x128 tile, BK=64, single 32KiB LDS buffer (4+ blocks/CU), loads for
// tile t+1 issued before compute of tile t. Conflict-free granule XOR.
// Two fused GEMM dispatches + XCD swizzle; shared-down split-K2 into f32
// partials summed in combine (no atomics).

#define H_DIM 2048
#define IMOE  1408
#define ISH   5632
#define NEXP  8
#define T_TOK 2048
#define TK_TOT (T_TOK * 2)

typedef __attribute__((ext_vector_type(8))) short short8;
typedef __attribute__((ext_vector_type(8))) __bf16 bf16x8;
typedef __attribute__((ext_vector_type(4))) float f32x4;

__device__ __forceinline__ float bf2f(unsigned short u) {
  union { unsigned int i; float f; } v; v.i = ((unsigned int)u) << 16; return v.f;
}
__device__ __forceinline__ unsigned short f2bf(float f) {
  union { float f; unsigned int i; } v; v.f = f;
  unsigned int x = v.i;
  return (unsigned short)((x + 0x7fffu + ((x >> 16) & 1u)) >> 16);
}

__device__ __forceinline__ f32x4 MFMA16(short8 a, short8 b, f32x4 c) {
  return __builtin_amdgcn_mfma_f32_16x16x32_bf16(
      __builtin_bit_cast(bf16x8, a), __builtin_bit_cast(bf16x8, b), c, 0, 0, 0);
}

__device__ __forceinline__ float silu_f(float x) { return x / (1.0f + __expf(-x)); }

// ---------------- conversion kernels ----------------

__global__ __launch_bounds__(256)
void transpose_cvt_kernel(const float* __restrict__ src, unsigned short* __restrict__ dst,
                          int R, int C, long sStride, long dStride) {
  src += (long)blockIdx.z * sStride;
  dst += (long)blockIdx.z * dStride;
  __shared__ float tile[32][33];
  int tx = threadIdx.x, ty = threadIdx.y;           // 32 x 8
  int x = blockIdx.x * 32 + tx;
  int yb = blockIdx.y * 32;
#pragma unroll
  for (int j = 0; j < 4; j++) {
    int y = yb + ty + j * 8;
    tile[ty + j * 8][tx] = src[(long)y * C + x];
  }
  __syncthreads();
  int c = blockIdx.x * 32 + ty;
  int r = yb + tx;
#pragma unroll
  for (int j = 0; j < 4; j++) {
    dst[(long)(c + j * 8) * R + r] = f2bf(tile[tx][ty + j * 8]);
  }
}

__global__ __launch_bounds__(256)
void cvt_x_kernel(const float* __restrict__ x, unsigned short* __restrict__ xb, int total4) {
  int i = blockIdx.x * 256 + threadIdx.x;
  if (i >= total4) return;
  float4 v = ((const float4*)x)[i];
  ushort4 o;
  o.x = f2bf(v.x); o.y = f2bf(v.y); o.z = f2bf(v.z); o.w = f2bf(v.w);
  ((ushort4*)xb)[i] = o;
}

// ---------------- routing ----------------

__global__ __launch_bounds__(256)
void router_kernel(const float* __restrict__ x, const float* __restrict__ Wr,
                   const float* __restrict__ Wsg, float* __restrict__ rw,
                   int* __restrict__ sel, float* __restrict__ sgate_sig,
                   int* __restrict__ counts) {
  int t = blockIdx.x;
  const float* xr = x + (long)t * H_DIM;
  float p[9];
#pragma unroll
  for (int e = 0; e < 9; e++) p[e] = 0.0f;
  for (int h = threadIdx.x; h < H_DIM; h += 256) {
    float xv = xr[h];
#pragma unroll
    for (int e = 0; e < 8; e++) p[e] += xv * Wr[e * H_DIM + h];
    p[8] += xv * Wsg[h];
  }
#pragma unroll
  for (int e = 0; e < 9; e++)
    for (int off = 32; off > 0; off >>= 1)
      p[e] += __shfl_down(p[e], off, 64);
  __shared__ float red[4][9];
  int wave = threadIdx.x >> 6, lane = threadIdx.x & 63;
  if (lane == 0) {
#pragma unroll
    for (int e = 0; e < 9; e++) red[wave][e] = p[e];
  }
  __syncthreads();
  if (threadIdx.x == 0) {
    float lg[9];
#pragma unroll
    for (int e = 0; e < 9; e++) lg[e] = red[0][e] + red[1][e] + red[2][e] + red[3][e];
    float m = lg[0];
#pragma unroll
    for (int e = 1; e < 8; e++) m = fmaxf(m, lg[e]);
    float pr[8], s = 0.0f;
#pragma unroll
    for (int e = 0; e < 8; e++) { pr[e] = expf(lg[e] - m); s += pr[e]; }
    float inv = 1.0f / s;
#pragma unroll
    for (int e = 0; e < 8; e++) pr[e] *= inv;
    int i0 = 0;
#pragma unroll
    for (int e = 1; e < 8; e++) if (pr[e] > pr[i0]) i0 = e;
    int i1 = (i0 == 0) ? 1 : 0;
#pragma unroll
    for (int e = 0; e < 8; e++) if (e != i0 && pr[e] > pr[i1]) i1 = e;
    rw[t * 2] = pr[i0]; rw[t * 2 + 1] = pr[i1];
    sel[t * 2] = i0;    sel[t * 2 + 1] = i1;
    sgate_sig[t] = 1.0f / (1.0f + expf(-lg[8]));
    atomicAdd(&counts[i0], 1);
    atomicAdd(&counts[i1], 1);
  }
}

__global__ void scan_kernel(const int* __restrict__ counts, int* __restrict__ offsets) {
  if (threadIdx.x == 0 && blockIdx.x == 0) {
    int s = 0;
    for (int e = 0; e < NEXP; e++) { offsets[e] = s; s += counts[e]; }
    offsets[NEXP] = s;
  }
}

__global__ __launch_bounds__(256)
void scatter_kernel(const int* __restrict__ sel, const int* __restrict__ offsets,
                    int* __restrict__ cursor, int* __restrict__ tok_of_slot,
                    int* __restrict__ slot_of_tok) {
  int t = blockIdx.x * 256 + threadIdx.x;
  if (t >= T_TOK) return;
#pragma unroll
  for (int k = 0; k < 2; k++) {
    int e = sel[t * 2 + k];
    int pos = atomicAdd(&cursor[e], 1);
    int slot = offsets[e] + pos;
    tok_of_slot[slot] = t;
    slot_of_tok[t * 2 + k] = slot;
  }
}

__global__ __launch_bounds__(256)
void gather_kernel(const unsigned short* __restrict__ xbf, const int* __restrict__ tok,
                   unsigned short* __restrict__ xg) {
  int i = blockIdx.x * 256 + threadIdx.x;   // slot*256 + col16B
  int slot = i >> 8, c8 = i & 255;
  long src = (long)tok[slot] * H_DIM + c8 * 8;
  ulonglong2 v = *(const ulonglong2*)(xbf + src);
  ((ulonglong2*)xg)[i] = v;
}

// ---------------- reg-staged 128x128 GEMM, BK=64 ----------------
// C[M,N] = A[M,K](bf16) * BT[N,K]^T(bf16). 256 thr = 4 waves (2x2), wave
// tile 64x64 (4x4 fragments, 2 k-slices). LDS: As/Bs [128 rows][8 granules
// of 16B] single-buffered; granule g of row r HOLDS global granule g^(r&7)
// (write-source swizzle; read applies same XOR -> conflict-free, bank = g*4,
// row stride 128B = bank-neutral).
// Loop: load regs(t+1) -> compute(t) -> barrier -> ds_write(t+1) -> barrier.
// PHASE 0 jobs: [0,1408) shared gate-up 16x88; [1408,4224) expert gate-up
//   8 x (16x22), A = pre-gathered xg. stores bf16.
// PHASE 1 jobs: [0,512) shared down 16x16x2 split-K -> sp partials (f32);
//   [512,2560) expert down 8 x (16x16) -> eo (f32).
template <int PHASE>
__global__ __launch_bounds__(256)
void moe_gemm_rs(const unsigned short* __restrict__ Ash,
                 const unsigned short* __restrict__ Bsh,
                 const unsigned short* __restrict__ Aex,
                 const unsigned short* __restrict__ Bex,
                 void* __restrict__ Csh, void* __restrict__ Cex,
                 const int* __restrict__ counts,
                 const int* __restrict__ offsets) {
  int o = blockIdx.x;
  int b = (o & 7) * (gridDim.x >> 3) + (o >> 3);   // XCD-aware bijective swizzle

  const unsigned short *A, *B;
  char* Cc;
  int N, Kld, NT, k0 = 0, row0, col0, rowbase = 0, cnt;
  if constexpr (PHASE == 0) {
    if (b < 1408) {
      A = Ash; B = Bsh; Cc = (char*)Csh;
      N = 2 * ISH; Kld = H_DIM; NT = H_DIM / 64;
      row0 = (b & 15) * 128; col0 = (b >> 4) * 128; cnt = T_TOK;
    } else {
      int b2 = b - 1408, e = b2 / 352, r2 = b2 % 352;
      cnt = counts[e]; row0 = (r2 & 15) * 128;
      if (row0 >= cnt) return;
      rowbase = offsets[e];
      A = Aex; B = Bex + (long)e * 2 * IMOE * H_DIM; Cc = (char*)Cex;
      N = 2 * IMOE; Kld = H_DIM; NT = H_DIM / 64;
      col0 = (r2 >> 4) * 128;
    }
  } else {
    if (b < 512) {
      int ks = b >> 8;
      A = Ash; B = Bsh;
      Cc = (char*)Csh + (size_t)ks * ((size_t)T_TOK * H_DIM * 4);
      N = H_DIM; Kld = ISH; NT = (ISH / 2) / 64; k0 = ks * (ISH / 2);
      row0 = (b & 15) * 128; col0 = ((b >> 4) & 15) * 128; cnt = T_TOK;
    } else {
      int b2 = b - 512, e = b2 >> 8, r2 = b2 & 255;
      cnt = counts[e]; row0 = (r2 & 15) * 128;
      if (row0 >= cnt) return;
      rowbase = offsets[e];
      A = Aex; B = Bex + (long)e * H_DIM * IMOE; Cc = (char*)Cex;
      N = H_DIM; Kld = IMOE; NT = IMOE / 64;
      col0 = ((r2 >> 4) & 15) * 128;
    }
  }

  __shared__ unsigned short As[128 * 64];
  __shared__ unsigned short Bs[128 * 64];

  int tid = threadIdx.x, wave = tid >> 6, lane = tid & 63;
  int wr = (wave >> 1) * 64, wc = (wave & 1) * 64;
  int fr = lane & 15, fg = lane >> 4;

  // staging: chunk c = tid + 256*j -> LDS row c>>3, granule c&7;
  // global source granule (c&7)^((c>>3)&7) of the same row (inverse swizzle).
  const unsigned short* aSrc[4];
  const unsigned short* bSrc[4];
  unsigned short* aDst[4];
  unsigned short* bDst[4];
#pragma unroll
  for (int j = 0; j < 4; j++) {
    int c = tid + 256 * j;
    int r = c >> 3, g = c & 7;
    int gg = g ^ (r & 7);
    long ar = row0 + r;
    if (ar > cnt - 1) ar = cnt - 1;
    ar += rowbase;
    aSrc[j] = A + ar * (long)Kld + k0 + gg * 8;
    bSrc[j] = B + (long)(col0 + r) * Kld + k0 + gg * 8;
    aDst[j] = &As[c * 8];
    bDst[j] = &Bs[c * 8];
  }

  // fragment read offsets (shorts): row*64 + (kgran ^ (row&7))*8
  int aOff[4][2], bOff[4][2];
#pragma unroll
  for (int m = 0; m < 4; m++) {
#pragma unroll
    for (int ks = 0; ks < 2; ks++) {
      int r = wr + m * 16 + fr;
      aOff[m][ks] = r * 64 + (((ks * 4 + fg) ^ (r & 7)) * 8);
      int cb = wc + m * 16 + fr;
      bOff[m][ks] = cb * 64 + (((ks * 4 + fg) ^ (cb & 7)) * 8);
    }
  }

  ulonglong2 ra0, ra1, ra2, ra3, rb0, rb1, rb2, rb3;
#define LOADT(t) do { long ko = (long)(t) * 64; \
    ra0 = *(const ulonglong2*)(aSrc[0] + ko); rb0 = *(const ulonglong2*)(bSrc[0] + ko); \
    ra1 = *(const ulonglong2*)(aSrc[1] + ko); rb1 = *(const ulonglong2*)(bSrc[1] + ko); \
    ra2 = *(const ulonglong2*)(aSrc[2] + ko); rb2 = *(const ulonglong2*)(bSrc[2] + ko); \
    ra3 = *(const ulonglong2*)(aSrc[3] + ko); rb3 = *(const ulonglong2*)(bSrc[3] + ko); } while (0)
#define WRITET() do { \
    *(ulonglong2*)aDst[0] = ra0; *(ulonglong2*)bDst[0] = rb0; \
    *(ulonglong2*)aDst[1] = ra1; *(ulonglong2*)bDst[1] = rb1; \
    *(ulonglong2*)aDst[2] = ra2; *(ulonglong2*)bDst[2] = rb2; \
    *(ulonglong2*)aDst[3] = ra3; *(ulonglong2*)bDst[3] = rb3; } while (0)

  f32x4 acc[4][4] = {};
#define COMPUTE() do { \
    _Pragma("unroll") for (int ks = 0; ks < 2; ks++) { \
      short8 aF[4], bF[4]; \
      _Pragma("unroll") for (int m = 0; m < 4; m++) aF[m] = *(const short8*)&As[aOff[m][ks]]; \
      _Pragma("unroll") for (int n = 0; n < 4; n++) bF[n] = *(const short8*)&Bs[bOff[n][ks]]; \
      _Pragma("unroll") for (int m = 0; m < 4; m++) \
        _Pragma("unroll") for (int n = 0; n < 4; n++) \
          acc[m][n] = MFMA16(aF[m], bF[n], acc[m][n]); \
    } } while (0)

  LOADT(0);
  WRITET();
  __syncthreads();
  for (int t = 1; t < NT; t++) {
    LOADT(t);        // issue loads for next tile (overlap with compute below)
    COMPUTE();       // consume current LDS tile
    __syncthreads(); // all reads done
    WRITET();        // compiler waits vmcnt here (loads long since issued)
    __syncthreads();
  }
  COMPUTE();         // last tile

  // ---- epilogue ----
  int rowguard = cnt - row0;
#pragma unroll
  for (int m = 0; m < 4; m++) {
    int rbase = wr + m * 16 + fg * 4;
#pragma unroll
    for (int n = 0; n < 4; n++) {
      int cg = col0 + wc + n * 16 + fr;
      f32x4 v = acc[m][n];
#pragma unroll
      for (int j = 0; j < 4; j++) {
        int rl = rbase + j;
        if (rl < rowguard) {
          long orow = (long)rowbase + row0 + rl;
          long ci = orow * (long)N + cg;
          if constexpr (PHASE == 0) ((unsigned short*)Cc)[ci] = f2bf(v[j]);
          else                      ((float*)Cc)[ci] = v[j];
        }
      }
    }
  }
#undef LOADT
#undef WRITET
#undef COMPUTE
}

// ---------------- elementwise ----------------

__global__ __launch_bounds__(256)
void silu2_kernel(const unsigned short* __restrict__ gu_sh, unsigned short* __restrict__ h_sh,
                  const unsigned short* __restrict__ gu_e, unsigned short* __restrict__ h_e) {
  int i = blockIdx.x * 256 + threadIdx.x;
  const int nsh = T_TOK * (ISH / 4);
  const unsigned short* g;
  unsigned short* h;
  int I, row, c4;
  if (i < nsh) {
    g = gu_sh; h = h_sh; I = ISH;
    row = i / (ISH / 4); c4 = i - row * (ISH / 4);
  } else {
    int j = i - nsh;
    g = gu_e; h = h_e; I = IMOE;
    row = j / (IMOE / 4); c4 = j - row * (IMOE / 4);
  }
  const unsigned short* gp = g + (long)row * 2 * I + c4 * 4;
  ushort4 gv = *(const ushort4*)gp;
  ushort4 uv = *(const ushort4*)(gp + I);
  ushort4 o2;
  o2.x = f2bf(silu_f(bf2f(gv.x)) * bf2f(uv.x));
  o2.y = f2bf(silu_f(bf2f(gv.y)) * bf2f(uv.y));
  o2.z = f2bf(silu_f(bf2f(gv.z)) * bf2f(uv.z));
  o2.w = f2bf(silu_f(bf2f(gv.w)) * bf2f(uv.w));
  *(ushort4*)(h + (long)row * I + c4 * 4) = o2;
}

// out = sgate[t]*(sp0+sp1) + w0*eo[s0] + w1*eo[s1]
__global__ __launch_bounds__(256)
void combine_kernel(float* __restrict__ out, const float* __restrict__ sp,
                    const float* __restrict__ eo, const int* __restrict__ slot_of_tok,
                    const float* __restrict__ rw, const float* __restrict__ sgate) {
  int i = blockIdx.x * 256 + threadIdx.x;
  const int h4n = H_DIM / 4;
  if (i >= T_TOK * h4n) return;
  int t = i / h4n;
  int h4 = i - t * h4n;
  int s0 = slot_of_tok[t * 2], s1 = slot_of_tok[t * 2 + 1];
  float w0 = rw[t * 2], w1 = rw[t * 2 + 1];
  float sg = sgate[t];
  float4 p0 = ((const float4*)sp)[i];
  float4 p1 = ((const float4*)sp)[(T_TOK * H_DIM / 4) + i];
  float4 a = ((const float4*)eo)[(long)s0 * h4n + h4];
  float4 bb = ((const float4*)eo)[(long)s1 * h4n + h4];
  float4 oo;
  oo.x = sg * (p0.x + p1.x) + w0 * a.x + w1 * bb.x;
  oo.y = sg * (p0.y + p1.y) + w0 * a.y + w1 * bb.y;
  oo.z = sg * (p0.z + p1.z) + w0 * a.z + w1 * bb.z;
  oo.w = sg * (p0.w + p1.w) + w0 * a.w + w1 * bb.w;
  ((float4*)out)[i] = oo;
}

// ---------------- host ----------------

extern "C" void kernel_launch(void* const* d_in, const int* in_sizes, int n_in,
                              void* d_out, int out_size, void* d_ws, size_t ws_size,
                              hipStream_t stream) {
  (void)in_sizes; (void)n_in; (void)out_size;
  const float* x    = (const float*)d_in[0];
  const float* Wr   = (const float*)d_in[1];
  const float* Wsg  = (const float*)d_in[2];
  const float* Wsgu = (const float*)d_in[3];
  const float* Wsd  = (const float*)d_in[4];
  const float* Wegu = (const float*)d_in[5];
  const float* Wed  = (const float*)d_in[6];
  float* out = (float*)d_out;

  char* ws = (char*)d_ws;
  size_t off = 0;
  auto alloc = [&](size_t b) { size_t o = off; off += (b + 255) & ~(size_t)255; return o; };

  size_t o_xbf   = alloc((size_t)T_TOK * H_DIM * 2);
  size_t o_WsguT = alloc((size_t)2 * ISH * H_DIM * 2);          // aliased as eo in P1
  size_t o_WsdT  = alloc((size_t)H_DIM * ISH * 2);
  size_t o_WeguT = alloc((size_t)NEXP * 2 * IMOE * H_DIM * 2);  // h_e aliases after P0
  size_t o_WedT  = alloc((size_t)NEXP * H_DIM * IMOE * 2);
  size_t o_gush  = alloc((size_t)T_TOK * 2 * ISH * 2);          // sp aliases after silu
  size_t o_hsh   = alloc((size_t)T_TOK * ISH * 2);
  size_t o_gue   = alloc((size_t)TK_TOT * 2 * IMOE * 2);
  size_t o_xg    = alloc((size_t)TK_TOT * H_DIM * 2);
  size_t o_ints  = alloc(256);
  size_t o_rw    = alloc((size_t)TK_TOT * 4);
  size_t o_sel   = alloc((size_t)TK_TOT * 4);
  size_t o_sg    = alloc((size_t)T_TOK * 4);
  size_t o_tok   = alloc((size_t)TK_TOT * 4);
  size_t o_s2t   = alloc((size_t)TK_TOT * 4);

  if (off > ws_size) {
    fprintf(stderr, "[moe kernel] workspace too small: need %zu have %zu\n", off, ws_size);
    return;
  }

  unsigned short* xbf   = (unsigned short*)(ws + o_xbf);
  unsigned short* WsguT = (unsigned short*)(ws + o_WsguT);
  unsigned short* WsdT  = (unsigned short*)(ws + o_WsdT);
  unsigned short* WeguT = (unsigned short*)(ws + o_WeguT);
  unsigned short* WedT  = (unsigned short*)(ws + o_WedT);
  unsigned short* gu_sh = (unsigned short*)(ws + o_gush);
  unsigned short* h_sh  = (unsigned short*)(ws + o_hsh);
  unsigned short* gu_e  = (unsigned short*)(ws + o_gue);
  unsigned short* xg    = (unsigned short*)(ws + o_xg);
  unsigned short* h_e   = (unsigned short*)(ws + o_WeguT);   // alias: dead after P0
  float* eo             = (float*)(ws + o_WsguT);            // alias: dead after P0
  float* sp             = (float*)(ws + o_gush);             // alias: gu_sh dead after silu

  int* ints    = (int*)(ws + o_ints);
  int* counts  = ints;
  int* cursor  = ints + 8;
  int* offsets = ints + 16;
  float* rw    = (float*)(ws + o_rw);
  int* sel     = (int*)(ws + o_sel);
  float* sgate = (float*)(ws + o_sg);
  int* tok     = (int*)(ws + o_tok);
  int* s2t     = (int*)(ws + o_s2t);

  dim3 tb(32, 8, 1);

  hipMemsetAsync(ints, 0, 256, stream);

  transpose_cvt_kernel<<<dim3(2 * ISH / 32, H_DIM / 32, 1), tb, 0, stream>>>(
      Wsgu, WsguT, H_DIM, 2 * ISH, 0, 0);
  transpose_cvt_kernel<<<dim3(H_DIM / 32, ISH / 32, 1), tb, 0, stream>>>(
      Wsd, WsdT, ISH, H_DIM, 0, 0);
  transpose_cvt_kernel<<<dim3(2 * IMOE / 32, H_DIM / 32, NEXP), tb, 0, stream>>>(
      Wegu, WeguT, H_DIM, 2 * IMOE, (long)H_DIM * 2 * IMOE, (long)2 * IMOE * H_DIM);
  transpose_cvt_kernel<<<dim3(H_DIM / 32, IMOE / 32, NEXP), tb, 0, stream>>>(
      Wed, WedT, IMOE, H_DIM, (long)IMOE * H_DIM, (long)H_DIM * IMOE);

  cvt_x_kernel<<<(T_TOK * H_DIM / 4) / 256, 256, 0, stream>>>(x, xbf, T_TOK * H_DIM / 4);

  router_kernel<<<T_TOK, 256, 0, stream>>>(x, Wr, Wsg, rw, sel, sgate, counts);
  scan_kernel<<<1, 64, 0, stream>>>(counts, offsets);
  scatter_kernel<<<(T_TOK + 255) / 256, 256, 0, stream>>>(sel, offsets, cursor, tok, s2t);
  gather_kernel<<<TK_TOT, 256, 0, stream>>>(xbf, tok, xg);

  // P0: fused gate-up, 1408 shared + 2816 expert = 4224 blocks
  moe_gemm_rs<0><<<4224, 256, 0, stream>>>(
      xbf, WsguT, xg, WeguT, gu_sh, gu_e, counts, offsets);

  {
    int total = T_TOK * (ISH / 4) + TK_TOT * (IMOE / 4);
    silu2_kernel<<<total / 256, 256, 0, stream>>>(gu_sh, h_sh, gu_e, h_e);
  }

  // P1: fused down, 512 shared (split-K2 -> sp) + 2048 expert (-> eo)
  moe_gemm_rs<1><<<2560, 256, 0, stream>>>(
      h_sh, WsdT, h_e, WedT, sp, eo, counts, offsets);

  combine_kernel<<<(T_TOK * H_DIM / 4) / 256, 256, 0, stream>>>(out, sp, eo, s2t, rw, sgate);
}

// Round 8
// 797.481 us; speedup vs baseline: 1.1986x; 1.1986x over previous
//
#include <hip/hip_runtime.h>
#include <cstdio>

// Qwen2 MoE sparse block, MI355X gfx950.
// Round 8: R2-verbatim gemm8 GEMM core (best measured total: 760us), plus:
// (1) silu fused into gate-up epilogue via INTERLEAVED gate/up weight
//     columns (gate_j->2j, up_j->2j+1) + __shfl_xor(1) pairing -> writes h
//     directly, no gu tensor, no silu dispatch;
// (2) pre-gathered xg so expert gate-up A is coalesced;
// (3) shared-down split-K4 atomic into zeroed out (R2), combine adds experts.

#define H_DIM 2048
#define IMOE  1408
#define ISH   5632
#define NEXP  8
#define T_TOK 2048
#define TK_TOT (T_TOK * 2)

typedef __attribute__((ext_vector_type(8))) short short8;
typedef __attribute__((ext_vector_type(8))) __bf16 bf16x8;
typedef __attribute__((ext_vector_type(4))) float f32x4;

__device__ __forceinline__ float bf2f(unsigned short u) {
  union { unsigned int i; float f; } v; v.i = ((unsigned int)u) << 16; return v.f;
}
__device__ __forceinline__ unsigned short f2bf(float f) {
  union { float f; unsigned int i; } v; v.f = f;
  unsigned int x = v.i;
  return (unsigned short)((x + 0x7fffu + ((x >> 16) & 1u)) >> 16);
}

__device__ __forceinline__ f32x4 MFMA16(short8 a, short8 b, f32x4 c) {
  return __builtin_amdgcn_mfma_f32_16x16x32_bf16(
      __builtin_bit_cast(bf16x8, a), __builtin_bit_cast(bf16x8, b), c, 0, 0, 0);
}

__device__ __forceinline__ void gload_lds16(const unsigned short* g, unsigned short* l) {
  __builtin_amdgcn_global_load_lds(
      (const __attribute__((address_space(1))) unsigned int*)g,
      (__attribute__((address_space(3))) unsigned int*)l, 16, 0, 0);
}

__device__ __forceinline__ float silu_f(float x) { return x / (1.0f + __expf(-x)); }

#define SBAR()   asm volatile("s_barrier" ::: "memory")
#define VMCNT(n) asm volatile("s_waitcnt vmcnt(" #n ")" ::: "memory")

// ---------------- conversion kernels ----------------

// fp32 [R][C] -> bf16 [C'][R]; if ILV, col c maps to c<I ? 2c : 2(c-I)+1
template <bool ILV>
__global__ __launch_bounds__(256)
void transpose_cvt_kernel(const float* __restrict__ src, unsigned short* __restrict__ dst,
                          int R, int C, int I, long sStride, long dStride) {
  src += (long)blockIdx.z * sStride;
  dst += (long)blockIdx.z * dStride;
  __shared__ float tile[32][33];
  int tx = threadIdx.x, ty = threadIdx.y;           // 32 x 8
  int x = blockIdx.x * 32 + tx;
  int yb = blockIdx.y * 32;
#pragma unroll
  for (int j = 0; j < 4; j++) {
    int y = yb + ty + j * 8;
    tile[ty + j * 8][tx] = src[(long)y * C + x];
  }
  __syncthreads();
  int r = yb + tx;
#pragma unroll
  for (int j = 0; j < 4; j++) {
    int c = blockIdx.x * 32 + ty + j * 8;
    int cd = ILV ? (c < I ? 2 * c : 2 * (c - I) + 1) : c;
    dst[(long)cd * R + r] = f2bf(tile[tx][ty + j * 8]);
  }
}

__global__ __launch_bounds__(256)
void cvt_x_kernel(const float* __restrict__ x, unsigned short* __restrict__ xb, int total4) {
  int i = blockIdx.x * 256 + threadIdx.x;
  if (i >= total4) return;
  float4 v = ((const float4*)x)[i];
  ushort4 o;
  o.x = f2bf(v.x); o.y = f2bf(v.y); o.z = f2bf(v.z); o.w = f2bf(v.w);
  ((ushort4*)xb)[i] = o;
}

// ---------------- routing ----------------

__global__ __launch_bounds__(256)
void router_kernel(const float* __restrict__ x, const float* __restrict__ Wr,
                   const float* __restrict__ Wsg, float* __restrict__ rw,
                   int* __restrict__ sel, float* __restrict__ sgate_sig,
                   int* __restrict__ counts) {
  int t = blockIdx.x;
  const float* xr = x + (long)t * H_DIM;
  float p[9];
#pragma unroll
  for (int e = 0; e < 9; e++) p[e] = 0.0f;
  for (int h = threadIdx.x; h < H_DIM; h += 256) {
    float xv = xr[h];
#pragma unroll
    for (int e = 0; e < 8; e++) p[e] += xv * Wr[e * H_DIM + h];
    p[8] += xv * Wsg[h];
  }
#pragma unroll
  for (int e = 0; e < 9; e++)
    for (int off = 32; off > 0; off >>= 1)
      p[e] += __shfl_down(p[e], off, 64);
  __shared__ float red[4][9];
  int wave = threadIdx.x >> 6, lane = threadIdx.x & 63;
  if (lane == 0) {
#pragma unroll
    for (int e = 0; e < 9; e++) red[wave][e] = p[e];
  }
  __syncthreads();
  if (threadIdx.x == 0) {
    float lg[9];
#pragma unroll
    for (int e = 0; e < 9; e++) lg[e] = red[0][e] + red[1][e] + red[2][e] + red[3][e];
    float m = lg[0];
#pragma unroll
    for (int e = 1; e < 8; e++) m = fmaxf(m, lg[e]);
    float pr[8], s = 0.0f;
#pragma unroll
    for (int e = 0; e < 8; e++) { pr[e] = expf(lg[e] - m); s += pr[e]; }
    float inv = 1.0f / s;
#pragma unroll
    for (int e = 0; e < 8; e++) pr[e] *= inv;
    int i0 = 0;
#pragma unroll
    for (int e = 1; e < 8; e++) if (pr[e] > pr[i0]) i0 = e;
    int i1 = (i0 == 0) ? 1 : 0;
#pragma unroll
    for (int e = 0; e < 8; e++) if (e != i0 && pr[e] > pr[i1]) i1 = e;
    rw[t * 2] = pr[i0]; rw[t * 2 + 1] = pr[i1];
    sel[t * 2] = i0;    sel[t * 2 + 1] = i1;
    sgate_sig[t] = 1.0f / (1.0f + expf(-lg[8]));
    atomicAdd(&counts[i0], 1);
    atomicAdd(&counts[i1], 1);
  }
}

__global__ void scan_kernel(const int* __restrict__ counts, int* __restrict__ offsets) {
  if (threadIdx.x == 0 && blockIdx.x == 0) {
    int s = 0;
    for (int e = 0; e < NEXP; e++) { offsets[e] = s; s += counts[e]; }
    offsets[NEXP] = s;
  }
}

__global__ __launch_bounds__(256)
void scatter_kernel(const int* __restrict__ sel, const int* __restrict__ offsets,
                    int* __restrict__ cursor, int* __restrict__ tok_of_slot,
                    int* __restrict__ slot_of_tok) {
  int t = blockIdx.x * 256 + threadIdx.x;
  if (t >= T_TOK) return;
#pragma unroll
  for (int k = 0; k < 2; k++) {
    int e = sel[t * 2 + k];
    int pos = atomicAdd(&cursor[e], 1);
    int slot = offsets[e] + pos;
    tok_of_slot[slot] = t;
    slot_of_tok[t * 2 + k] = slot;
  }
}

__global__ __launch_bounds__(256)
void gather_kernel(const unsigned short* __restrict__ xbf, const int* __restrict__ tok,
                   unsigned short* __restrict__ xg) {
  int i = blockIdx.x * 256 + threadIdx.x;   // slot*256 + col16B
  int slot = i >> 8, c8 = i & 255;
  long src = (long)tok[slot] * H_DIM + c8 * 8;
  ulonglong2 v = *(const ulonglong2*)(xbf + src);
  ((ulonglong2*)xg)[i] = v;
}

// ---------------- 256x256 deep-pipelined GEMM (R2 core) ----------------
// C[M,N] = A[M,K](bf16) * BT[N,K]^T(bf16). 512 thr = 8 waves, wave out
// 128x64. BK=32, 4 LDS buffers; stage tile t+3 while computing t; vmcnt(8).
// EPI: 1 = unsafeAtomicAdd f32 * rowscale[row]; 2 = store f32;
//      3 = silu-pair: cols are interleaved (gate,up); even-fr lanes store
//          bf16 silu(gate)*up at col cg>>1 of an N/2-wide h matrix.
template <int EPI, bool EXPERT, bool GATHER>
__global__ __launch_bounds__(512, 2)
void gemm8_kernel(const unsigned short* __restrict__ A,
                  const unsigned short* __restrict__ BT,
                  void* __restrict__ Cv,
                  int N, int Kld, int KLEN, int M,
                  const int* __restrict__ counts, const int* __restrict__ offsets,
                  const int* __restrict__ tok_of_slot,
                  const float* __restrict__ rowscale, long bt_estride) {
  __shared__ unsigned short lds8[65536];  // 128 KiB

  int cnt = M, rowbase = 0, k0 = 0;
  const unsigned short* bt = BT;
  if constexpr (EXPERT) {
    int e = blockIdx.z;
    cnt = counts[e];
    rowbase = offsets[e];
    bt += (long)e * bt_estride;
  } else {
    k0 = blockIdx.z * KLEN;
  }
  int row0 = blockIdx.x * 256;
  if (row0 >= cnt) return;
  int col0 = blockIdx.y * 256;

  int tid = threadIdx.x, wave = tid >> 6, lane = tid & 63;
  int NT = KLEN / 32;

  const unsigned short* aSrc[2];
  const unsigned short* bSrc[2];
#pragma unroll
  for (int i = 0; i < 2; i++) {
    int r = i * 128 + (tid >> 2);
    int sw = (((tid & 3) ^ ((r >> 1) & 3)) * 8);
    long arow;
    if constexpr (EXPERT) {
      int s = rowbase + min(row0 + r, cnt - 1);
      arow = GATHER ? tok_of_slot[s] : s;
    } else {
      arow = row0 + r;
    }
    aSrc[i] = A + arow * (long)Kld + k0 + sw;
    bSrc[i] = bt + (long)(col0 + r) * Kld + k0 + sw;
  }
  int dA0 = wave * 512, dA1 = 4096 + wave * 512;
  int dB0 = 8192 + wave * 512, dB1 = 12288 + wave * 512;

  auto STAGE_A = [&](int u) {
    int b2 = (u & 3) * 16384;
    long kk = (long)min(u, NT - 1) * 32;
    gload_lds16(aSrc[0] + kk, &lds8[b2 + dA0]);
    gload_lds16(aSrc[1] + kk, &lds8[b2 + dA1]);
  };
  auto STAGE_B = [&](int u) {
    int b2 = (u & 3) * 16384;
    long kk = (long)min(u, NT - 1) * 32;
    gload_lds16(bSrc[0] + kk, &lds8[b2 + dB0]);
    gload_lds16(bSrc[1] + kk, &lds8[b2 + dB1]);
  };

  int wr = wave >> 2, wc = wave & 3;
  int fr = lane & 15, fg = lane >> 4;
  int addrA0[4], addrA1[4], addrB[4];
#pragma unroll
  for (int m = 0; m < 4; m++) {
    int rl0 = wr * 128 + m * 16 + fr;
    int rl1 = rl0 + 64;
    int cl  = wc * 64 + m * 16 + fr;
    addrA0[m] = rl0 * 32 + ((fg ^ ((rl0 >> 1) & 3)) * 8);
    addrA1[m] = rl1 * 32 + ((fg ^ ((rl1 >> 1) & 3)) * 8);
    addrB[m]  = 8192 + cl * 32 + ((fg ^ ((cl >> 1) & 3)) * 8);
  }

  STAGE_A(0); STAGE_B(0);
  STAGE_A(1); STAGE_B(1);
  STAGE_A(2); STAGE_B(2);
  VMCNT(8);
  SBAR();

  f32x4 acc[8][4] = {};

  for (int t = 0; t < NT; t++) {
    int b = (t & 3) * 16384;
    int u = t + 3;
    short8 Bf[4], Af[4];
#pragma unroll
    for (int n = 0; n < 4; n++) Bf[n] = *(const short8*)&lds8[b + addrB[n]];
#pragma unroll
    for (int m = 0; m < 4; m++) Af[m] = *(const short8*)&lds8[b + addrA0[m]];
    STAGE_A(u);
    SBAR();
    __builtin_amdgcn_s_setprio(1);
#pragma unroll
    for (int m = 0; m < 4; m++)
#pragma unroll
      for (int n = 0; n < 4; n++)
        acc[m][n] = MFMA16(Af[m], Bf[n], acc[m][n]);
    __builtin_amdgcn_s_setprio(0);
    SBAR();
#pragma unroll
    for (int m = 0; m < 4; m++) Af[m] = *(const short8*)&lds8[b + addrA1[m]];
    STAGE_B(u);
    SBAR();
    __builtin_amdgcn_s_setprio(1);
#pragma unroll
    for (int m = 0; m < 4; m++)
#pragma unroll
      for (int n = 0; n < 4; n++)
        acc[4 + m][n] = MFMA16(Af[m], Bf[n], acc[4 + m][n]);
    __builtin_amdgcn_s_setprio(0);
    VMCNT(8);
    SBAR();
  }
  VMCNT(0);

  // ---- epilogue ----
  int rowguard = cnt - row0;
#pragma unroll
  for (int mq = 0; mq < 8; mq++) {
    int rl = wr * 128 + (mq >> 2) * 64 + (mq & 3) * 16 + fg * 4;
#pragma unroll
    for (int n = 0; n < 4; n++) {
      int cg = col0 + wc * 64 + n * 16 + fr;
      f32x4 v = acc[mq][n];
#pragma unroll
      for (int j = 0; j < 4; j++) {
        int r = rl + j;
        float pv = __shfl_xor(v[j], 1);   // pair value (all lanes execute)
        if (r < rowguard) {
          long orow = (long)rowbase + row0 + r;
          if constexpr (EPI == 1) {
            unsafeAtomicAdd(&((float*)Cv)[orow * (long)N + cg], v[j] * rowscale[orow]);
          } else if constexpr (EPI == 2) {
            ((float*)Cv)[orow * (long)N + cg] = v[j];
          } else {   // EPI == 3: silu(gate)*up, even-fr lanes hold gate
            if (!(fr & 1)) {
              float hval = silu_f(v[j]) * pv;
              ((unsigned short*)Cv)[orow * (long)(N >> 1) + (cg >> 1)] = f2bf(hval);
            }
          }
        }
      }
    }
  }
}

// ---------------- combine ----------------

// out(already = gated shared sum via atomics) += w0*eo[s0] + w1*eo[s1]
__global__ __launch_bounds__(256)
void combine_kernel(float* __restrict__ out, const float* __restrict__ eo,
                    const int* __restrict__ slot_of_tok, const float* __restrict__ rw) {
  int i = blockIdx.x * 256 + threadIdx.x;
  const int h4n = H_DIM / 4;
  if (i >= T_TOK * h4n) return;
  int t = i / h4n;
  int h4 = i - t * h4n;
  int s0 = slot_of_tok[t * 2], s1 = slot_of_tok[t * 2 + 1];
  float w0 = rw[t * 2], w1 = rw[t * 2 + 1];
  float4 o = ((float4*)out)[i];
  float4 a = ((const float4*)eo)[(long)s0 * h4n + h4];
  float4 b = ((const float4*)eo)[(long)s1 * h4n + h4];
  o.x += w0 * a.x + w1 * b.x;
  o.y += w0 * a.y + w1 * b.y;
  o.z += w0 * a.z + w1 * b.z;
  o.w += w0 * a.w + w1 * b.w;
  ((float4*)out)[i] = o;
}

// ---------------- host ----------------

extern "C" void kernel_launch(void* const* d_in, const int* in_sizes, int n_in,
                              void* d_out, int out_size, void* d_ws, size_t ws_size,
                              hipStream_t stream) {
  (void)in_sizes; (void)n_in; (void)out_size;
  const float* x    = (const float*)d_in[0];
  const float* Wr   = (const float*)d_in[1];
  const float* Wsg  = (const float*)d_in[2];
  const float* Wsgu = (const float*)d_in[3];
  const float* Wsd  = (const float*)d_in[4];
  const float* Wegu = (const float*)d_in[5];
  const float* Wed  = (const float*)d_in[6];
  float* out = (float*)d_out;

  char* ws = (char*)d_ws;
  size_t off = 0;
  auto alloc = [&](size_t b) { size_t o = off; off += (b + 255) & ~(size_t)255; return o; };

  size_t o_xbf   = alloc((size_t)T_TOK * H_DIM * 2);
  size_t o_WsguT = alloc((size_t)2 * ISH * H_DIM * 2);          // aliased as eo after P0
  size_t o_WsdT  = alloc((size_t)H_DIM * ISH * 2);
  size_t o_WeguT = alloc((size_t)NEXP * 2 * IMOE * H_DIM * 2);
  size_t o_WedT  = alloc((size_t)NEXP * H_DIM * IMOE * 2);
  size_t o_hsh   = alloc((size_t)T_TOK * ISH * 2);
  size_t o_he    = alloc((size_t)TK_TOT * IMOE * 2);
  size_t o_xg    = alloc((size_t)TK_TOT * H_DIM * 2);
  size_t o_ints  = alloc(256);
  size_t o_rw    = alloc((size_t)TK_TOT * 4);
  size_t o_sel   = alloc((size_t)TK_TOT * 4);
  size_t o_sg    = alloc((size_t)T_TOK * 4);
  size_t o_tok   = alloc((size_t)TK_TOT * 4);
  size_t o_s2t   = alloc((size_t)TK_TOT * 4);

  if (off > ws_size) {
    fprintf(stderr, "[moe kernel] workspace too small: need %zu have %zu\n", off, ws_size);
    return;
  }

  unsigned short* xbf   = (unsigned short*)(ws + o_xbf);
  unsigned short* WsguT = (unsigned short*)(ws + o_WsguT);
  unsigned short* WsdT  = (unsigned short*)(ws + o_WsdT);
  unsigned short* WeguT = (unsigned short*)(ws + o_WeguT);
  unsigned short* WedT  = (unsigned short*)(ws + o_WedT);
  unsigned short* h_sh  = (unsigned short*)(ws + o_hsh);
  unsigned short* h_e   = (unsigned short*)(ws + o_he);
  unsigned short* xg    = (unsigned short*)(ws + o_xg);
  float* eo             = (float*)(ws + o_WsguT);   // alias: WsguT dead after P0

  int* ints    = (int*)(ws + o_ints);
  int* counts  = ints;
  int* cursor  = ints + 8;
  int* offsets = ints + 16;
  float* rw    = (float*)(ws + o_rw);
  int* sel     = (int*)(ws + o_sel);
  float* sgate = (float*)(ws + o_sg);
  int* tok     = (int*)(ws + o_tok);
  int* s2t     = (int*)(ws + o_s2t);

  dim3 tb(32, 8, 1);

  hipMemsetAsync(ints, 0, 64, stream);
  hipMemsetAsync(out, 0, (size_t)T_TOK * H_DIM * 4, stream);   // atomic target

  // weight conversion: gate-up transposes use interleaved columns (EPI=3)
  transpose_cvt_kernel<true><<<dim3(2 * ISH / 32, H_DIM / 32, 1), tb, 0, stream>>>(
      Wsgu, WsguT, H_DIM, 2 * ISH, ISH, 0, 0);
  transpose_cvt_kernel<false><<<dim3(H_DIM / 32, ISH / 32, 1), tb, 0, stream>>>(
      Wsd, WsdT, ISH, H_DIM, 0, 0, 0);
  transpose_cvt_kernel<true><<<dim3(2 * IMOE / 32, H_DIM / 32, NEXP), tb, 0, stream>>>(
      Wegu, WeguT, H_DIM, 2 * IMOE, IMOE, (long)H_DIM * 2 * IMOE, (long)2 * IMOE * H_DIM);
  transpose_cvt_kernel<false><<<dim3(H_DIM / 32, IMOE / 32, NEXP), tb, 0, stream>>>(
      Wed, WedT, IMOE, H_DIM, 0, (long)IMOE * H_DIM, (long)H_DIM * IMOE);

  cvt_x_kernel<<<(T_TOK * H_DIM / 4) / 256, 256, 0, stream>>>(x, xbf, T_TOK * H_DIM / 4);

  router_kernel<<<T_TOK, 256, 0, stream>>>(x, Wr, Wsg, rw, sel, sgate, counts);
  scan_kernel<<<1, 64, 0, stream>>>(counts, offsets);
  scatter_kernel<<<(T_TOK + 255) / 256, 256, 0, stream>>>(sel, offsets, cursor, tok, s2t);
  gather_kernel<<<TK_TOT, 256, 0, stream>>>(xbf, tok, xg);

  // shared gate-up (+fused silu) -> h_sh [T][ISH] bf16
  gemm8_kernel<3, false, false><<<dim3(T_TOK / 256, 2 * ISH / 256, 1), 512, 0, stream>>>(
      xbf, WsguT, h_sh, 2 * ISH, H_DIM, H_DIM, T_TOK,
      nullptr, nullptr, nullptr, nullptr, 0);

  // expert gate-up (+fused silu), A = pre-gathered xg -> h_e [slots][IMOE]
  gemm8_kernel<3, true, false><<<dim3(T_TOK / 256, 2 * IMOE / 256, NEXP), 512, 0, stream>>>(
      xg, WeguT, h_e, 2 * IMOE, H_DIM, H_DIM, 0,
      counts, offsets, nullptr, nullptr, (long)2 * IMOE * H_DIM);

  // shared down, split-K=4, gated atomic accumulate into zeroed out
  gemm8_kernel<1, false, false><<<dim3(T_TOK / 256, H_DIM / 256, 4), 512, 0, stream>>>(
      h_sh, WsdT, out, H_DIM, ISH, ISH / 4, T_TOK,
      nullptr, nullptr, nullptr, sgate, 0);

  // expert down -> eo f32
  gemm8_kernel<2, true, false><<<dim3(T_TOK / 256, H_DIM / 256, NEXP), 512, 0, stream>>>(
      h_e, WedT, eo, H_DIM, IMOE, IMOE, 0,
      counts, offsets, nullptr, nullptr, (long)H_DIM * IMOE);

  combine_kernel<<<(T_TOK * H_DIM / 4) / 256, 256, 0, stream>>>(out, eo, s2t, rw);
}

// Round 9
// 775.908 us; speedup vs baseline: 1.2319x; 1.0278x over previous
//
#include <hip/hip_runtime.h>
#include <cstdio>

// Qwen2 MoE sparse block, MI355X gfx950.
// Round 9: GEMM core = guide's verified minimum 2-phase template (T3/m230):
// per BK=64 tile {STAGE next-tile first; ds_read frags; lgkm; 64-MFMA;
// vmcnt(0); ONE barrier}. 2 LDS buffers (128 KiB). 3x fewer barriers and
// 2x fewer stall events per K than R8. Conversions interleaved with their
// consuming GEMMs for L3 residency. Fused silu epilogue kept (R8-verified).

#define H_DIM 2048
#define IMOE  1408
#define ISH   5632
#define NEXP  8
#define T_TOK 2048
#define TK_TOT (T_TOK * 2)

typedef __attribute__((ext_vector_type(8))) short short8;
typedef __attribute__((ext_vector_type(8))) __bf16 bf16x8;
typedef __attribute__((ext_vector_type(4))) float f32x4;

__device__ __forceinline__ float bf2f(unsigned short u) {
  union { unsigned int i; float f; } v; v.i = ((unsigned int)u) << 16; return v.f;
}
__device__ __forceinline__ unsigned short f2bf(float f) {
  union { float f; unsigned int i; } v; v.f = f;
  unsigned int x = v.i;
  return (unsigned short)((x + 0x7fffu + ((x >> 16) & 1u)) >> 16);
}

__device__ __forceinline__ f32x4 MFMA16(short8 a, short8 b, f32x4 c) {
  return __builtin_amdgcn_mfma_f32_16x16x32_bf16(
      __builtin_bit_cast(bf16x8, a), __builtin_bit_cast(bf16x8, b), c, 0, 0, 0);
}

__device__ __forceinline__ void gload_lds16(const unsigned short* g, unsigned short* l) {
  __builtin_amdgcn_global_load_lds(
      (const __attribute__((address_space(1))) unsigned int*)g,
      (__attribute__((address_space(3))) unsigned int*)l, 16, 0, 0);
}

__device__ __forceinline__ float silu_f(float x) { return x / (1.0f + __expf(-x)); }

#define SBAR()   asm volatile("s_barrier" ::: "memory")
#define VMCNT(n) asm volatile("s_waitcnt vmcnt(" #n ")" ::: "memory")

// ---------------- conversion kernels ----------------

// fp32 [R][C] -> bf16 [C'][R]; if ILV, col c maps to c<I ? 2c : 2(c-I)+1
template <bool ILV>
__global__ __launch_bounds__(256)
void transpose_cvt_kernel(const float* __restrict__ src, unsigned short* __restrict__ dst,
                          int R, int C, int I, long sStride, long dStride) {
  src += (long)blockIdx.z * sStride;
  dst += (long)blockIdx.z * dStride;
  __shared__ float tile[32][33];
  int tx = threadIdx.x, ty = threadIdx.y;           // 32 x 8
  int x = blockIdx.x * 32 + tx;
  int yb = blockIdx.y * 32;
#pragma unroll
  for (int j = 0; j < 4; j++) {
    int y = yb + ty + j * 8;
    tile[ty + j * 8][tx] = src[(long)y * C + x];
  }
  __syncthreads();
  int r = yb + tx;
#pragma unroll
  for (int j = 0; j < 4; j++) {
    int c = blockIdx.x * 32 + ty + j * 8;
    int cd = ILV ? (c < I ? 2 * c : 2 * (c - I) + 1) : c;
    dst[(long)cd * R + r] = f2bf(tile[tx][ty + j * 8]);
  }
}

__global__ __launch_bounds__(256)
void cvt_x_kernel(const float* __restrict__ x, unsigned short* __restrict__ xb, int total4) {
  int i = blockIdx.x * 256 + threadIdx.x;
  if (i >= total4) return;
  float4 v = ((const float4*)x)[i];
  ushort4 o;
  o.x = f2bf(v.x); o.y = f2bf(v.y); o.z = f2bf(v.z); o.w = f2bf(v.w);
  ((ushort4*)xb)[i] = o;
}

// ---------------- routing ----------------

__global__ __launch_bounds__(256)
void router_kernel(const float* __restrict__ x, const float* __restrict__ Wr,
                   const float* __restrict__ Wsg, float* __restrict__ rw,
                   int* __restrict__ sel, float* __restrict__ sgate_sig,
                   int* __restrict__ counts) {
  int t = blockIdx.x;
  const float* xr = x + (long)t * H_DIM;
  float p[9];
#pragma unroll
  for (int e = 0; e < 9; e++) p[e] = 0.0f;
  for (int h = threadIdx.x; h < H_DIM; h += 256) {
    float xv = xr[h];
#pragma unroll
    for (int e = 0; e < 8; e++) p[e] += xv * Wr[e * H_DIM + h];
    p[8] += xv * Wsg[h];
  }
#pragma unroll
  for (int e = 0; e < 9; e++)
    for (int off = 32; off > 0; off >>= 1)
      p[e] += __shfl_down(p[e], off, 64);
  __shared__ float red[4][9];
  int wave = threadIdx.x >> 6, lane = threadIdx.x & 63;
  if (lane == 0) {
#pragma unroll
    for (int e = 0; e < 9; e++) red[wave][e] = p[e];
  }
  __syncthreads();
  if (threadIdx.x == 0) {
    float lg[9];
#pragma unroll
    for (int e = 0; e < 9; e++) lg[e] = red[0][e] + red[1][e] + red[2][e] + red[3][e];
    float m = lg[0];
#pragma unroll
    for (int e = 1; e < 8; e++) m = fmaxf(m, lg[e]);
    float pr[8], s = 0.0f;
#pragma unroll
    for (int e = 0; e < 8; e++) { pr[e] = expf(lg[e] - m); s += pr[e]; }
    float inv = 1.0f / s;
#pragma unroll
    for (int e = 0; e < 8; e++) pr[e] *= inv;
    int i0 = 0;
#pragma unroll
    for (int e = 1; e < 8; e++) if (pr[e] > pr[i0]) i0 = e;
    int i1 = (i0 == 0) ? 1 : 0;
#pragma unroll
    for (int e = 0; e < 8; e++) if (e != i0 && pr[e] > pr[i1]) i1 = e;
    rw[t * 2] = pr[i0]; rw[t * 2 + 1] = pr[i1];
    sel[t * 2] = i0;    sel[t * 2 + 1] = i1;
    sgate_sig[t] = 1.0f / (1.0f + expf(-lg[8]));
    atomicAdd(&counts[i0], 1);
    atomicAdd(&counts[i1], 1);
  }
}

__global__ void scan_kernel(const int* __restrict__ counts, int* __restrict__ offsets) {
  if (threadIdx.x == 0 && blockIdx.x == 0) {
    int s = 0;
    for (int e = 0; e < NEXP; e++) { offsets[e] = s; s += counts[e]; }
    offsets[NEXP] = s;
  }
}

__global__ __launch_bounds__(256)
void scatter_kernel(const int* __restrict__ sel, const int* __restrict__ offsets,
                    int* __restrict__ cursor, int* __restrict__ tok_of_slot,
                    int* __restrict__ slot_of_tok) {
  int t = blockIdx.x * 256 + threadIdx.x;
  if (t >= T_TOK) return;
#pragma unroll
  for (int k = 0; k < 2; k++) {
    int e = sel[t * 2 + k];
    int pos = atomicAdd(&cursor[e], 1);
    int slot = offsets[e] + pos;
    tok_of_slot[slot] = t;
    slot_of_tok[t * 2 + k] = slot;
  }
}

__global__ __launch_bounds__(256)
void gather_kernel(const unsigned short* __restrict__ xbf, const int* __restrict__ tok,
                   unsigned short* __restrict__ xg) {
  int i = blockIdx.x * 256 + threadIdx.x;   // slot*256 + col16B
  int slot = i >> 8, c8 = i & 255;
  long src = (long)tok[slot] * H_DIM + c8 * 8;
  ulonglong2 v = *(const ulonglong2*)(xbf + src);
  ((ulonglong2*)xg)[i] = v;
}

// ---------------- 256x256 2-phase GEMM, BK=64 (T3 minimum template) ----------------
// C[M,N] = A[M,K](bf16) * BT[N,K]^T(bf16). 512 thr = 8 waves (2Mx4N), wave
// tile 128x64, acc 8x4, 64 MFMA/wave/tile (2 k-slices of 32).
// LDS: 2 bufs x (A 256x64 + B 256x64) bf16 = 128 KiB. Stage = 8 gload_lds
// (4 A-sites + 4 B-sites of 64 rows). 16B-granule XOR swizzle:
// source granule (tid&7)^(row&7); read granule (ks*4+fg)^(fr&7) -> 2-way
// (free) bank pattern. Iter: STAGE(t+1) -> ds_read -> [lgkm] -> 64 MFMA
// (setprio) -> vmcnt(0) -> s_barrier.
// EPI: 1 = unsafeAtomicAdd f32 * rowscale; 2 = f32 store; 3 = silu-pair bf16.
template <int EPI, bool EXPERT>
__global__ __launch_bounds__(512, 2)
void gemm2p_kernel(const unsigned short* __restrict__ A,
                   const unsigned short* __restrict__ BT,
                   void* __restrict__ Cv,
                   int N, int Kld, int KLEN, int M,
                   const int* __restrict__ counts, const int* __restrict__ offsets,
                   const float* __restrict__ rowscale, long bt_estride) {
  __shared__ unsigned short lds8[65536];  // 128 KiB: A bufs at 0,16384; B at 32768,49152

  int cnt = M, rowbase = 0, k0 = 0;
  const unsigned short* bt = BT;
  if constexpr (EXPERT) {
    int e = blockIdx.z;
    cnt = counts[e];
    rowbase = offsets[e];
    bt += (long)e * bt_estride;
  } else {
    k0 = blockIdx.z * KLEN;
  }
  int row0 = blockIdx.x * 256;
  if (row0 >= cnt) return;
  int col0 = blockIdx.y * 256;

  int tid = threadIdx.x, wave = tid >> 6, lane = tid & 63;
  int NT = KLEN / 64;

  // staging sources: op s covers rows s*64 + (tid>>3); granule (tid&7)^(row&7)
  const unsigned short* aSrc[4];
  const unsigned short* bSrc[4];
#pragma unroll
  for (int s = 0; s < 4; s++) {
    int r = s * 64 + (tid >> 3);
    int g = (tid & 7) ^ (r & 7);
    long ar = row0 + r;
    if (ar > cnt - 1) ar = cnt - 1;
    ar += rowbase;
    aSrc[s] = A + ar * (long)Kld + k0 + g * 8;
    bSrc[s] = bt + (long)(col0 + r) * Kld + k0 + g * 8;
  }

  // fragment ds_read offsets (shorts), within a buffer
  int wr = wave >> 2, wc = wave & 3;
  int fr = lane & 15, fg = lane >> 4;
  int aOff[8][2], bOff[4][2];
#pragma unroll
  for (int ks = 0; ks < 2; ks++) {
    int q = ((ks * 4 + fg) ^ (fr & 7)) * 8;
#pragma unroll
    for (int m = 0; m < 8; m++) aOff[m][ks] = (wr * 128 + m * 16 + fr) * 64 + q;
#pragma unroll
    for (int n = 0; n < 4; n++) bOff[n][ks] = (wc * 64 + n * 16 + fr) * 64 + q;
  }

#define STAGE(p, t) do { long kk = (long)(t) * 64; \
    _Pragma("unroll") for (int s = 0; s < 4; s++) { \
      gload_lds16(aSrc[s] + kk, &lds8[(p) * 16384 + s * 4096 + wave * 512]); \
      gload_lds16(bSrc[s] + kk, &lds8[32768 + (p) * 16384 + s * 4096 + wave * 512]); \
    } } while (0)

  f32x4 acc[8][4] = {};

  // prologue: stage tile 0 into buf 0
  STAGE(0, 0);
  VMCNT(0);
  SBAR();

  for (int t = 0; t < NT; t++) {
    int p = t & 1;
    if (t + 1 < NT) STAGE(p ^ 1, t + 1);   // issue next tile first (T3)
#pragma unroll
    for (int ks = 0; ks < 2; ks++) {
      short8 aF[8], bF[4];
#pragma unroll
      for (int m = 0; m < 8; m++) aF[m] = *(const short8*)&lds8[p * 16384 + aOff[m][ks]];
#pragma unroll
      for (int n = 0; n < 4; n++) bF[n] = *(const short8*)&lds8[32768 + p * 16384 + bOff[n][ks]];
      __builtin_amdgcn_s_setprio(1);
#pragma unroll
      for (int m = 0; m < 8; m++)
#pragma unroll
        for (int n = 0; n < 4; n++)
          acc[m][n] = MFMA16(aF[m], bF[n], acc[m][n]);
      __builtin_amdgcn_s_setprio(0);
    }
    VMCNT(0);   // next buffer fully staged
    SBAR();     // all reads of buf p done; safe to overwrite next iter
  }

  // ---- epilogue ----
  int rowguard = cnt - row0;
#pragma unroll
  for (int m = 0; m < 8; m++) {
    int rl = wr * 128 + m * 16 + fg * 4;
#pragma unroll
    for (int n = 0; n < 4; n++) {
      int cg = col0 + wc * 64 + n * 16 + fr;
      f32x4 v = acc[m][n];
#pragma unroll
      for (int j = 0; j < 4; j++) {
        int r = rl + j;
        float pv = __shfl_xor(v[j], 1);   // pair value (all lanes execute)
        if (r < rowguard) {
          long orow = (long)rowbase + row0 + r;
          if constexpr (EPI == 1) {
            unsafeAtomicAdd(&((float*)Cv)[orow * (long)N + cg], v[j] * rowscale[orow]);
          } else if constexpr (EPI == 2) {
            ((float*)Cv)[orow * (long)N + cg] = v[j];
          } else {   // EPI == 3: interleaved (gate,up); even-fr lanes store
            if (!(fr & 1)) {
              float hval = silu_f(v[j]) * pv;
              ((unsigned short*)Cv)[orow * (long)(N >> 1) + (cg >> 1)] = f2bf(hval);
            }
          }
        }
      }
    }
  }
#undef STAGE
}

// ---------------- combine ----------------

// out(already = gated shared sum via atomics) += w0*eo[s0] + w1*eo[s1]
__global__ __launch_bounds__(256)
void combine_kernel(float* __restrict__ out, const float* __restrict__ eo,
                    const int* __restrict__ slot_of_tok, const float* __restrict__ rw) {
  int i = blockIdx.x * 256 + threadIdx.x;
  const int h4n = H_DIM / 4;
  if (i >= T_TOK * h4n) return;
  int t = i / h4n;
  int h4 = i - t * h4n;
  int s0 = slot_of_tok[t * 2], s1 = slot_of_tok[t * 2 + 1];
  float w0 = rw[t * 2], w1 = rw[t * 2 + 1];
  float4 o = ((float4*)out)[i];
  float4 a = ((const float4*)eo)[(long)s0 * h4n + h4];
  float4 b = ((const float4*)eo)[(long)s1 * h4n + h4];
  o.x += w0 * a.x + w1 * b.x;
  o.y += w0 * a.y + w1 * b.y;
  o.z += w0 * a.z + w1 * b.z;
  o.w += w0 * a.w + w1 * b.w;
  ((float4*)out)[i] = o;
}

// ---------------- host ----------------

extern "C" void kernel_launch(void* const* d_in, const int* in_sizes, int n_in,
                              void* d_out, int out_size, void* d_ws, size_t ws_size,
                              hipStream_t stream) {
  (void)in_sizes; (void)n_in; (void)out_size;
  const float* x    = (const float*)d_in[0];
  const float* Wr   = (const float*)d_in[1];
  const float* Wsg  = (const float*)d_in[2];
  const float* Wsgu = (const float*)d_in[3];
  const float* Wsd  = (const float*)d_in[4];
  const float* Wegu = (const float*)d_in[5];
  const float* Wed  = (const float*)d_in[6];
  float* out = (float*)d_out;

  char* ws = (char*)d_ws;
  size_t off = 0;
  auto alloc = [&](size_t b) { size_t o = off; off += (b + 255) & ~(size_t)255; return o; };

  size_t o_xbf   = alloc((size_t)T_TOK * H_DIM * 2);
  size_t o_WsguT = alloc((size_t)2 * ISH * H_DIM * 2);          // aliased as eo later
  size_t o_WsdT  = alloc((size_t)H_DIM * ISH * 2);
  size_t o_WeguT = alloc((size_t)NEXP * 2 * IMOE * H_DIM * 2);
  size_t o_WedT  = alloc((size_t)NEXP * H_DIM * IMOE * 2);
  size_t o_hsh   = alloc((size_t)T_TOK * ISH * 2);
  size_t o_he    = alloc((size_t)TK_TOT * IMOE * 2);
  size_t o_xg    = alloc((size_t)TK_TOT * H_DIM * 2);
  size_t o_ints  = alloc(256);
  size_t o_rw    = alloc((size_t)TK_TOT * 4);
  size_t o_sel   = alloc((size_t)TK_TOT * 4);
  size_t o_sg    = alloc((size_t)T_TOK * 4);
  size_t o_tok   = alloc((size_t)TK_TOT * 4);
  size_t o_s2t   = alloc((size_t)TK_TOT * 4);

  if (off > ws_size) {
    fprintf(stderr, "[moe kernel] workspace too small: need %zu have %zu\n", off, ws_size);
    return;
  }

  unsigned short* xbf   = (unsigned short*)(ws + o_xbf);
  unsigned short* WsguT = (unsigned short*)(ws + o_WsguT);
  unsigned short* WsdT  = (unsigned short*)(ws + o_WsdT);
  unsigned short* WeguT = (unsigned short*)(ws + o_WeguT);
  unsigned short* WedT  = (unsigned short*)(ws + o_WedT);
  unsigned short* h_sh  = (unsigned short*)(ws + o_hsh);
  unsigned short* h_e   = (unsigned short*)(ws + o_he);
  unsigned short* xg    = (unsigned short*)(ws + o_xg);
  float* eo             = (float*)(ws + o_WsguT);   // alias: WsguT dead after sh/e gate-up

  int* ints    = (int*)(ws + o_ints);
  int* counts  = ints;
  int* cursor  = ints + 8;
  int* offsets = ints + 16;
  float* rw    = (float*)(ws + o_rw);
  int* sel     = (int*)(ws + o_sel);
  float* sgate = (float*)(ws + o_sg);
  int* tok     = (int*)(ws + o_tok);
  int* s2t     = (int*)(ws + o_s2t);

  dim3 tb(32, 8, 1);

  hipMemsetAsync(ints, 0, 64, stream);
  hipMemsetAsync(out, 0, (size_t)T_TOK * H_DIM * 4, stream);   // atomic target

  // small prep first
  cvt_x_kernel<<<(T_TOK * H_DIM / 4) / 256, 256, 0, stream>>>(x, xbf, T_TOK * H_DIM / 4);
  router_kernel<<<T_TOK, 256, 0, stream>>>(x, Wr, Wsg, rw, sel, sgate, counts);
  scan_kernel<<<1, 64, 0, stream>>>(counts, offsets);
  scatter_kernel<<<(T_TOK + 255) / 256, 256, 0, stream>>>(sel, offsets, cursor, tok, s2t);
  gather_kernel<<<TK_TOT, 256, 0, stream>>>(xbf, tok, xg);

  // --- convert then immediately consume (L3 residency) ---

  // shared gate-up (interleaved cols) -> sh-gu GEMM (+fused silu) -> h_sh
  transpose_cvt_kernel<true><<<dim3(2 * ISH / 32, H_DIM / 32, 1), tb, 0, stream>>>(
      Wsgu, WsguT, H_DIM, 2 * ISH, ISH, 0, 0);
  gemm2p_kernel<3, false><<<dim3(T_TOK / 256, 2 * ISH / 256, 1), 512, 0, stream>>>(
      xbf, WsguT, h_sh, 2 * ISH, H_DIM, H_DIM, T_TOK, nullptr, nullptr, nullptr, 0);

  // expert gate-up (interleaved) -> e-gu GEMM (+fused silu) -> h_e
  transpose_cvt_kernel<true><<<dim3(2 * IMOE / 32, H_DIM / 32, NEXP), tb, 0, stream>>>(
      Wegu, WeguT, H_DIM, 2 * IMOE, IMOE, (long)H_DIM * 2 * IMOE, (long)2 * IMOE * H_DIM);
  gemm2p_kernel<3, true><<<dim3(T_TOK / 256, 2 * IMOE / 256, NEXP), 512, 0, stream>>>(
      xg, WeguT, h_e, 2 * IMOE, H_DIM, H_DIM, 0, counts, offsets, nullptr,
      (long)2 * IMOE * H_DIM);

  // shared down -> split-K=4 gated atomic accumulate into zeroed out
  transpose_cvt_kernel<false><<<dim3(H_DIM / 32, ISH / 32, 1), tb, 0, stream>>>(
      Wsd, WsdT, ISH, H_DIM, 0, 0, 0);
  gemm2p_kernel<1, false><<<dim3(T_TOK / 256, H_DIM / 256, 4), 512, 0, stream>>>(
      h_sh, WsdT, out, H_DIM, ISH, ISH / 4, T_TOK, nullptr, nullptr, sgate, 0);

  // expert down -> eo f32
  transpose_cvt_kernel<false><<<dim3(H_DIM / 32, IMOE / 32, NEXP), tb, 0, stream>>>(
      Wed, WedT, IMOE, H_DIM, 0, (long)IMOE * H_DIM, (long)H_DIM * IMOE);
  gemm2p_kernel<2, true><<<dim3(T_TOK / 256, H_DIM / 256, NEXP), 512, 0, stream>>>(
      h_e, WedT, eo, H_DIM, IMOE, IMOE, 0, counts, offsets, nullptr,
      (long)H_DIM * IMOE);

  combine_kernel<<<(T_TOK * H_DIM / 4) / 256, 256, 0, stream>>>(out, eo, s2t, rw);
}